// Round 4
// baseline (434.994 us; speedup 1.0000x reference)
//
#include <hip/hip_runtime.h>
#include <math.h>

#define BATCH 16
#define SEQL  256
#define HDIM  64
#define NBLK  2
#define PADID 49999
#define NEGV  -4294967295.0f
#define LNEPS 1e-8f
#define INV_SQRT_HS 0.17677669529663687f
#define TKC   257              // cols per head in Tk
#define TKW   (2*TKC)          // 514 floats per Tk row
#define QT    8                // queries per attn block

__device__ __forceinline__ float waveReduceSum(float v) {
#pragma unroll
    for (int o = 32; o > 0; o >>= 1) v += __shfl_xor(v, o);
    return v;
}

// 4 rows per 256-thread block (one row per wave): LN1 + Q/Kp/Vp projections.
__global__ __launch_bounds__(256) void prep_kernel(
    const float* __restrict__ xin, const int* __restrict__ seqs_data,
    const int* __restrict__ positions,
    const float* __restrict__ Qw, const float* __restrict__ Qb,
    const float* __restrict__ Kw, const float* __restrict__ Kb,
    const float* __restrict__ Vw, const float* __restrict__ Vb,
    const float* __restrict__ g1, const float* __restrict__ b1,
    const float* __restrict__ apK, const float* __restrict__ apV,
    float* __restrict__ q_in, float* __restrict__ Qo,
    float* __restrict__ Kp, float* __restrict__ Vp,
    int apply_keep)
{
    const int w = threadIdx.x >> 6;
    const int t = threadIdx.x & 63;
    const int row = blockIdx.x * 4 + w;
    float x = xin[(size_t)row * HDIM + t];
    if (apply_keep && seqs_data[row] == PADID) x = 0.f;

    float mean = waveReduceSum(x) * (1.f / HDIM);
    float d = x - mean;
    float var = waveReduceSum(d * d) * (1.f / HDIM);
    float q = g1[t] * d / sqrtf(var + LNEPS) + b1[t];

    __shared__ float xs[4][HDIM];
    __shared__ float qs[4][HDIM];
    xs[w][t] = x; qs[w][t] = q;           // per-wave slice: no __syncthreads needed
    q_in[(size_t)row * HDIM + t] = q;

    int pos = positions[row];
    float aK = pos ? apK[(size_t)pos * HDIM + t] : 0.f;
    float aV = pos ? apV[(size_t)pos * HDIM + t] : 0.f;

    const float4* qw4 = (const float4*)(Qw + (size_t)t * HDIM);
    const float4* kw4 = (const float4*)(Kw + (size_t)t * HDIM);
    const float4* vw4 = (const float4*)(Vw + (size_t)t * HDIM);
    float aq = 0.f, ak = 0.f, av = 0.f;
#pragma unroll
    for (int j = 0; j < 16; ++j) {
        float4 wq = qw4[j], wk = kw4[j], wv = vw4[j];
        float q0 = qs[w][4*j+0], q1 = qs[w][4*j+1], q2 = qs[w][4*j+2], q3 = qs[w][4*j+3];
        float y0 = xs[w][4*j+0], y1 = xs[w][4*j+1], y2 = xs[w][4*j+2], y3 = xs[w][4*j+3];
        aq += q0*wq.x + q1*wq.y + q2*wq.z + q3*wq.w;
        ak += y0*wk.x + y1*wk.y + y2*wk.z + y3*wk.w;
        av += y0*wv.x + y1*wv.y + y2*wv.z + y3*wv.w;
    }
    Qo[(size_t)row * HDIM + t] = aq + Qb[t];
    Kp[(size_t)row * HDIM + t] = ak + Kb[t] + aK;
    Vp[(size_t)row * HDIM + t] = av + Vb[t] + aV;
}

// Tk[r][h*257+c] = sum_d Q[r][h*32+d] * tKtab[c][h*32+d].
// Block: 16 rows; thread c holds tKtab col (both heads) in 64 regs, Q via s_load.
__global__ __launch_bounds__(256) void tk_kernel(
    const float* __restrict__ Qo, const float* __restrict__ tKtab,
    float* __restrict__ Tk)
{
    const int r0 = blockIdx.x * 16;
    for (int c = threadIdx.x; c < TKC; c += 256) {
        float tc[64];
#pragma unroll
        for (int dd = 0; dd < 64; ++dd) tc[dd] = tKtab[(size_t)c * HDIM + dd];
        for (int i = 0; i < 16; ++i) {
            const int r = r0 + i;
            const float4* q4 = (const float4*)(Qo + (size_t)r * HDIM); // uniform -> s_load
            float a0 = 0.f, a1 = 0.f;
#pragma unroll
            for (int j = 0; j < 8; ++j) {
                float4 qv = q4[j];
                a0 += tc[4*j+0]*qv.x + tc[4*j+1]*qv.y + tc[4*j+2]*qv.z + tc[4*j+3]*qv.w;
            }
#pragma unroll
            for (int j = 8; j < 16; ++j) {
                float4 qv = q4[j];
                a1 += tc[4*j+0]*qv.x + tc[4*j+1]*qv.y + tc[4*j+2]*qv.z + tc[4*j+3]*qv.w;
            }
            Tk[(size_t)r * TKW + c]       = a0;
            Tk[(size_t)r * TKW + TKC + c] = a1;
        }
    }
}

// Attention: 8 queries per 256-thread block.  Thread m holds Kp[m] in regs
// (reused across 8 queries); time-K term via scalar Tk gather; batched softmax;
// output phase skips masked (A==0) pairs with a wave-uniform branch.
__global__ __launch_bounds__(256) void attn_kernel(
    const float* __restrict__ Qo, const float* __restrict__ Kp,
    const float* __restrict__ Vp, const float* __restrict__ q_in,
    const float* __restrict__ Tk, const int* __restrict__ seqs_data,
    const int* __restrict__ tmat, const float* __restrict__ tVtab,
    float* __restrict__ x2)
{
    const int blk = blockIdx.x;
    const int b   = blk >> 5;
    const int l0  = (blk & 31) << 3;
    const int row0 = b * SEQL + l0;
    const int tid = threadIdx.x;
    const int m = tid;
    const int lane = tid & 63, wv = tid >> 6;

    __shared__ float A_s[QT][2][SEQL];
    __shared__ int   tm_s[QT][SEQL];
    __shared__ float outred[4][QT][HDIM];
    __shared__ float redm[QT][2][4];
    __shared__ float reds[QT][2][4];

    // Kp row -> registers
    float kp[64];
    const float4* kp4 = (const float4*)(Kp + (size_t)(b * SEQL + m) * HDIM);
#pragma unroll
    for (int j = 0; j < 16; ++j) {
        float4 v = kp4[j];
        kp[4*j] = v.x; kp[4*j+1] = v.y; kp[4*j+2] = v.z; kp[4*j+3] = v.w;
    }
    int tmc[QT];
#pragma unroll
    for (int li = 0; li < QT; ++li) {
        tmc[li] = tmat[(size_t)(row0 + li) * SEQL + m];
        tm_s[li][m] = tmc[li];
    }

    // ---- scores ----
    float s0v[QT], s1v[QT];
#pragma unroll
    for (int li = 0; li < QT; ++li) {
        const int l = l0 + li;
        const float4* q4 = (const float4*)(Qo + (size_t)(row0 + li) * HDIM); // uniform
        float s0 = 0.f, s1 = 0.f;
#pragma unroll
        for (int j = 0; j < 8; ++j) {
            float4 qv = q4[j];
            s0 += kp[4*j+0]*qv.x + kp[4*j+1]*qv.y + kp[4*j+2]*qv.z + kp[4*j+3]*qv.w;
        }
#pragma unroll
        for (int j = 8; j < 16; ++j) {
            float4 qv = q4[j];
            s1 += kp[4*j+0]*qv.x + kp[4*j+1]*qv.y + kp[4*j+2]*qv.z + kp[4*j+3]*qv.w;
        }
        const float* tkrow = Tk + (size_t)(row0 + li) * TKW;
        s0 = (s0 + tkrow[tmc[li]]) * INV_SQRT_HS;
        s1 = (s1 + tkrow[TKC + tmc[li]]) * INV_SQRT_HS;
        const bool masked = (m > l) || (seqs_data[row0 + li] == PADID);
        s0v[li] = masked ? NEGV : s0;
        s1v[li] = masked ? NEGV : s1;
    }
    // batched softmax: wave max -> LDS -> block max; exp; wave sum -> LDS -> block sum
#pragma unroll
    for (int li = 0; li < QT; ++li) {
        float a0 = s0v[li], a1 = s1v[li];
#pragma unroll
        for (int o = 32; o > 0; o >>= 1) {
            a0 = fmaxf(a0, __shfl_xor(a0, o));
            a1 = fmaxf(a1, __shfl_xor(a1, o));
        }
        if (lane == 0) { redm[li][0][wv] = a0; redm[li][1][wv] = a1; }
    }
    __syncthreads();
#pragma unroll
    for (int li = 0; li < QT; ++li) {
        float m0 = fmaxf(fmaxf(redm[li][0][0], redm[li][0][1]),
                         fmaxf(redm[li][0][2], redm[li][0][3]));
        float m1 = fmaxf(fmaxf(redm[li][1][0], redm[li][1][1]),
                         fmaxf(redm[li][1][2], redm[li][1][3]));
        float p0 = __expf(s0v[li] - m0), p1 = __expf(s1v[li] - m1);
        s0v[li] = p0; s1v[li] = p1;
        float t0 = waveReduceSum(p0), t1 = waveReduceSum(p1);
        if (lane == 0) { reds[li][0][wv] = t0; reds[li][1][wv] = t1; }
    }
    __syncthreads();
#pragma unroll
    for (int li = 0; li < QT; ++li) {
        float sum0 = reds[li][0][0] + reds[li][0][1] + reds[li][0][2] + reds[li][0][3];
        float sum1 = reds[li][1][0] + reds[li][1][1] + reds[li][1][2] + reds[li][1][3];
        A_s[li][0][m] = s0v[li] / sum0;
        A_s[li][1][m] = s1v[li] / sum1;
    }
    __syncthreads();

    // ---- output ----
    const int chunk = tid >> 6;
    const int hd = tid & 63;
    const int h = hd >> 5;
    float acc[QT];
#pragma unroll
    for (int li = 0; li < QT; ++li) acc[li] = 0.f;
    const float* vpb = Vp + (size_t)b * SEQL * HDIM + hd;
    for (int i = 0; i < 64; ++i) {
        const int mm = 4 * i + chunk;
        float vp = vpb[(size_t)mm * HDIM];
#pragma unroll
        for (int li = 0; li < QT; ++li) {
            float a = A_s[li][h][mm];
            if (a != 0.f) {   // wave-uniform: masked entries are exactly 0
                float tv = tVtab[(size_t)tm_s[li][mm] * HDIM + hd];
                acc[li] += a * (vp + tv);
            }
        }
    }
#pragma unroll
    for (int li = 0; li < QT; ++li) outred[chunk][li][hd] = acc[li];
    __syncthreads();
#pragma unroll
    for (int r = 0; r < 2; ++r) {
        const int li = r * 4 + (tid >> 6);
        const int d = tid & 63;
        const int row = row0 + li;
        float o = outred[0][li][d] + outred[1][li][d] + outred[2][li][d] + outred[3][li][d];
        x2[(size_t)row * HDIM + d] = q_in[(size_t)row * HDIM + d] + o;
    }
}

// 4 rows per block: LN2 + FFN + residual + keep; optional fused final LN.
__global__ __launch_bounds__(256) void ffn_kernel(
    const float* __restrict__ x2, const int* __restrict__ seqs_data,
    const float* __restrict__ g2, const float* __restrict__ bg2,
    const float* __restrict__ W1, const float* __restrict__ bb1,
    const float* __restrict__ W2, const float* __restrict__ bb2,
    const float* __restrict__ lg, const float* __restrict__ lb,
    float* __restrict__ xout, float* __restrict__ dout, int final_ln)
{
    const int w = threadIdx.x >> 6;
    const int t = threadIdx.x & 63;
    const int row = blockIdx.x * 4 + w;
    float x = x2[(size_t)row * HDIM + t];
    float mean = waveReduceSum(x) * (1.f / HDIM);
    float d = x - mean;
    float var = waveReduceSum(d * d) * (1.f / HDIM);
    float s = g2[t] * d / sqrtf(var + LNEPS) + bg2[t];

    __shared__ float ss[4][HDIM];
    __shared__ float hs[4][HDIM];
    ss[w][t] = s;
    const float4* w14 = (const float4*)(W1 + (size_t)t * HDIM);
    float acc = 0.f;
#pragma unroll
    for (int j = 0; j < 16; ++j) {
        float4 wq = w14[j];
        acc += ss[w][4*j]*wq.x + ss[w][4*j+1]*wq.y + ss[w][4*j+2]*wq.z + ss[w][4*j+3]*wq.w;
    }
    float hval = fmaxf(acc + bb1[t], 0.f);
    hs[w][t] = hval;
    const float4* w24 = (const float4*)(W2 + (size_t)t * HDIM);
    float acc2 = 0.f;
#pragma unroll
    for (int j = 0; j < 16; ++j) {
        float4 wq = w24[j];
        acc2 += hs[w][4*j]*wq.x + hs[w][4*j+1]*wq.y + hs[w][4*j+2]*wq.z + hs[w][4*j+3]*wq.w;
    }
    float y = acc2 + bb2[t] + s;
    if (seqs_data[row] == PADID) y = 0.f;
    if (final_ln) {
        float m2 = waveReduceSum(y) * (1.f / HDIM);
        float dd = y - m2;
        float v2 = waveReduceSum(dd * dd) * (1.f / HDIM);
        dout[(size_t)row * HDIM + t] = lg[t] * dd / sqrtf(v2 + LNEPS) + lb[t];
    } else {
        xout[(size_t)row * HDIM + t] = y;
    }
}

extern "C" void kernel_launch(void* const* d_in, const int* in_sizes, int n_in,
                              void* d_out, int out_size, void* d_ws, size_t ws_size,
                              hipStream_t stream) {
    const int*   seqs_data = (const int*)d_in[0];
    const float* seqs      = (const float*)d_in[1];
    const int*   positions = (const int*)d_in[2];
    const int*   tmat      = (const int*)d_in[3];
    const float* apK       = (const float*)d_in[4];
    const float* apV       = (const float*)d_in[5];
    const float* tKtab     = (const float*)d_in[6];
    const float* tVtab     = (const float*)d_in[7];
    const float* Qw = (const float*)d_in[8];
    const float* Qb = (const float*)d_in[9];
    const float* Kw = (const float*)d_in[10];
    const float* Kb = (const float*)d_in[11];
    const float* Vw = (const float*)d_in[12];
    const float* Vb = (const float*)d_in[13];
    const float* g1 = (const float*)d_in[14];
    const float* b1 = (const float*)d_in[15];
    const float* g2 = (const float*)d_in[16];
    const float* b2 = (const float*)d_in[17];
    const float* W1 = (const float*)d_in[18];
    const float* fb1 = (const float*)d_in[19];
    const float* W2 = (const float*)d_in[20];
    const float* fb2 = (const float*)d_in[21];
    const float* lastg = (const float*)d_in[22];
    const float* lastb = (const float*)d_in[23];

    const size_t N = (size_t)BATCH * SEQL * HDIM;   // 262144
    float* ws   = (float*)d_ws;
    float* x    = ws;
    float* q_in = ws + 1 * N;
    float* Qo   = ws + 2 * N;
    float* Kp   = ws + 3 * N;
    float* Vp   = ws + 4 * N;
    float* Tk   = ws + 5 * N;   // 4096 x 514 floats = 8.42 MB

    const int rows = BATCH * SEQL;   // 4096

    for (int i = 0; i < NBLK; ++i) {
        const float* xin = (i == 0) ? seqs : x;
        prep_kernel<<<rows / 4, 256, 0, stream>>>(
            xin, seqs_data, positions,
            Qw + (size_t)i * HDIM * HDIM, Qb + (size_t)i * HDIM,
            Kw + (size_t)i * HDIM * HDIM, Kb + (size_t)i * HDIM,
            Vw + (size_t)i * HDIM * HDIM, Vb + (size_t)i * HDIM,
            g1 + (size_t)i * HDIM, b1 + (size_t)i * HDIM,
            apK, apV, q_in, Qo, Kp, Vp, (i == 0) ? 1 : 0);
        tk_kernel<<<rows / 16, 256, 0, stream>>>(Qo, tKtab, Tk);
        attn_kernel<<<rows / QT, 256, 0, stream>>>(
            Qo, Kp, Vp, q_in, Tk, seqs_data, tmat, tVtab, x);
        ffn_kernel<<<rows / 4, 256, 0, stream>>>(
            x, seqs_data, g2 + (size_t)i * HDIM, b2 + (size_t)i * HDIM,
            W1 + (size_t)i * HDIM * HDIM, fb1 + (size_t)i * HDIM,
            W2 + (size_t)i * HDIM * HDIM, fb2 + (size_t)i * HDIM,
            lastg, lastb, x, (float*)d_out, (i == NBLK - 1) ? 1 : 0);
    }
}

// Round 5
// 274.841 us; speedup vs baseline: 1.5827x; 1.5827x over previous
//
#include <hip/hip_runtime.h>
#include <math.h>

#define BATCH 16
#define SEQL  256
#define HDIM  64
#define NBLK  2
#define PADID 49999
#define NEGV  -4294967295.0f
#define LNEPS 1e-8f
#define INV_SQRT_HS 0.17677669529663687f
#define TKC   257
#define TKW   (2*TKC)          // 514
#define TKTLD 260              // padded leading dim of tKtabT
#define QG    4                // queries per attn block

__device__ __forceinline__ float waveReduceSum(float v) {
#pragma unroll
    for (int o = 32; o > 0; o >>= 1) v += __shfl_xor(v, o);
    return v;
}

// One-shot transposes: 10 64x64 weight matrices + tKtab (257x64 -> 64x260).
__global__ __launch_bounds__(256) void setup_kernel(
    const float* __restrict__ Qw, const float* __restrict__ Kw,
    const float* __restrict__ Vw, const float* __restrict__ W1,
    const float* __restrict__ W2, const float* __restrict__ tKtab,
    float* __restrict__ QwT, float* __restrict__ KwT, float* __restrict__ VwT,
    float* __restrict__ W1T, float* __restrict__ W2T, float* __restrict__ tKtabT)
{
    __shared__ float tile[64][65];
    const int tid = threadIdx.x;
    const int blk = blockIdx.x;
    if (blk < 10) {
        const float* srcs[10] = {Qw, Qw+4096, Kw, Kw+4096, Vw, Vw+4096,
                                 W1, W1+4096, W2, W2+4096};
        float*       dsts[10] = {QwT, QwT+4096, KwT, KwT+4096, VwT, VwT+4096,
                                 W1T, W1T+4096, W2T, W2T+4096};
        const float* s = srcs[blk];
        float*       d = dsts[blk];
        for (int p = 0; p < 16; ++p) {
            int r = p*4 + (tid>>6), c = tid&63;
            tile[r][c] = s[r*64 + c];
        }
        __syncthreads();
        for (int p = 0; p < 16; ++p) {
            int mth = p*4 + (tid>>6), t = tid&63;
            d[mth*64 + t] = tile[t][mth];
        }
    } else {
        const int s0 = (blk - 10) * 64;
        const int nrows = min(64, TKC - s0);
        for (int p = 0; p < 16; ++p) {
            int rr = p*4 + (tid>>6), c = tid&63;
            if (rr < nrows) tile[rr][c] = tKtab[(size_t)(s0+rr)*64 + c];
        }
        __syncthreads();
        for (int p = 0; p < 16; ++p) {
            int dd = p*4 + (tid>>6), cc = tid&63;
            if (cc < nrows) tKtabT[dd*TKTLD + s0 + cc] = tile[cc][dd];
        }
    }
}

// 4 rows/block: LN1 + Q/Kp/Vp projections with transposed (coalesced) weights.
// Also emits KpT (feature-major) via in-LDS transpose.
__global__ __launch_bounds__(256) void prep_kernel(
    const float* __restrict__ xin, const int* __restrict__ seqs_data,
    const int* __restrict__ positions,
    const float* __restrict__ QwT, const float* __restrict__ Qb,
    const float* __restrict__ KwT, const float* __restrict__ Kb,
    const float* __restrict__ VwT, const float* __restrict__ Vb,
    const float* __restrict__ g1, const float* __restrict__ b1,
    const float* __restrict__ apK, const float* __restrict__ apV,
    float* __restrict__ q_in, float* __restrict__ Qo,
    float* __restrict__ KpT, float* __restrict__ Vp,
    int apply_keep)
{
    const int w = threadIdx.x >> 6;
    const int t = threadIdx.x & 63;
    const int row0 = blockIdx.x * 4;
    const int row = row0 + w;
    float x = xin[(size_t)row * HDIM + t];
    if (apply_keep && seqs_data[row] == PADID) x = 0.f;

    float mean = waveReduceSum(x) * (1.f / HDIM);
    float d = x - mean;
    float var = waveReduceSum(d * d) * (1.f / HDIM);
    float q = g1[t] * d / sqrtf(var + LNEPS) + b1[t];

    __shared__ float xs[4][HDIM];
    __shared__ float qs[4][HDIM];
    __shared__ float kx[HDIM][5];
    xs[w][t] = x; qs[w][t] = q;            // same-wave write/read
    q_in[(size_t)row * HDIM + t] = q;

    int pos = positions[row];
    float aK = pos ? apK[(size_t)pos * HDIM + t] : 0.f;
    float aV = pos ? apV[(size_t)pos * HDIM + t] : 0.f;

    float aq = 0.f, ak = 0.f, av = 0.f;
#pragma unroll 16
    for (int mth = 0; mth < 64; ++mth) {
        float qm = qs[w][mth], xm = xs[w][mth];
        aq += qm * QwT[mth*64 + t];
        ak += xm * KwT[mth*64 + t];
        av += xm * VwT[mth*64 + t];
    }
    Qo[(size_t)row * HDIM + t] = aq + Qb[t];
    Vp[(size_t)row * HDIM + t] = av + Vb[t] + aV;
    kx[t][w] = ak + Kb[t] + aK;
    __syncthreads();
    const int f = threadIdx.x >> 2, j = threadIdx.x & 3;
    KpT[(size_t)f * 4096 + row0 + j] = kx[f][j];
}

// Tk[r][h*257+c] = Q[r,h] . tKtab[c,h], via coalesced tKtabT column loads.
__global__ __launch_bounds__(256) void tk_kernel(
    const float* __restrict__ Qo, const float* __restrict__ tKtabT,
    float* __restrict__ Tk)
{
    const int r0 = blockIdx.x * 8;
    const int tid = threadIdx.x;
    float tc[64];
#pragma unroll
    for (int dd = 0; dd < 64; ++dd) tc[dd] = tKtabT[dd*TKTLD + tid];   // coalesced
    for (int i = 0; i < 8; ++i) {
        const int r = r0 + i;
        const float4* q4 = (const float4*)(Qo + (size_t)r * HDIM);     // uniform -> s_load
        float a0 = 0.f, a1 = 0.f;
#pragma unroll
        for (int jj = 0; jj < 8; ++jj) {
            float4 qv = q4[jj];
            a0 += tc[4*jj+0]*qv.x + tc[4*jj+1]*qv.y + tc[4*jj+2]*qv.z + tc[4*jj+3]*qv.w;
        }
#pragma unroll
        for (int jj = 8; jj < 16; ++jj) {
            float4 qv = q4[jj];
            a1 += tc[4*jj+0]*qv.x + tc[4*jj+1]*qv.y + tc[4*jj+2]*qv.z + tc[4*jj+3]*qv.w;
        }
        Tk[(size_t)r * TKW + tid]       = a0;
        Tk[(size_t)r * TKW + TKC + tid] = a1;
    }
    if (tid == 0) {   // tail column c = 256
#pragma unroll
        for (int dd = 0; dd < 64; ++dd) tc[dd] = tKtabT[dd*TKTLD + 256];
        for (int i = 0; i < 8; ++i) {
            const int r = r0 + i;
            const float* qp = Qo + (size_t)r * HDIM;
            float a0 = 0.f, a1 = 0.f;
            for (int dd = 0; dd < 32; ++dd) a0 += tc[dd] * qp[dd];
            for (int dd = 32; dd < 64; ++dd) a1 += tc[dd] * qp[dd];
            Tk[(size_t)r * TKW + 256]       = a0;
            Tk[(size_t)r * TKW + TKC + 256] = a1;
        }
    }
}

// Attention, QG=4 queries per 256-thread block (grid 1024).
// Scores: coalesced KpT regs + scalar Tk gather.  Softmax batched.
// A scattered into LDS histogram W[li][h][c] (atomicAdd); output = dense
// coalesced sweeps over Vp rows (causal-truncated) + tVtab rows (zero-skipped).
__global__ __launch_bounds__(256) void attn_kernel(
    const float* __restrict__ Qo, const float* __restrict__ KpT,
    const float* __restrict__ Vp, const float* __restrict__ q_in,
    const float* __restrict__ Tk, const int* __restrict__ seqs_data,
    const int* __restrict__ tmat, const float* __restrict__ tVtab,
    float* __restrict__ x2)
{
    const int blk = blockIdx.x;
    const int b   = blk >> 6;
    const int l0  = (blk & 63) << 2;
    const int row0 = b * SEQL + l0;
    const int tid = threadIdx.x;
    const int m = tid;
    const int lane = tid & 63, wv = tid >> 6;

    __shared__ float A_s[QG][2][SEQL];
    __shared__ float Wl[QG][2][TKTLD];
    __shared__ float outred[4][QG][HDIM];
    __shared__ float redm[QG][2][4];
    __shared__ float reds[QG][2][4];

    for (int k = tid; k < QG*2*TKTLD; k += 256) ((float*)Wl)[k] = 0.f;

    bool qpad[QG]; bool anypad = false;
#pragma unroll
    for (int li = 0; li < QG; ++li) {
        qpad[li] = (seqs_data[row0 + li] == PADID);
        anypad |= qpad[li];
    }
    const int lmax = l0 + QG - 1;

    float kp[64];
    if ((m <= lmax) || anypad) {
#pragma unroll
        for (int dd = 0; dd < 64; ++dd)
            kp[dd] = KpT[(size_t)dd * 4096 + b * SEQL + m];   // coalesced
    } else {
#pragma unroll
        for (int dd = 0; dd < 64; ++dd) kp[dd] = 0.f;
    }
    int tmc[QG];
#pragma unroll
    for (int li = 0; li < QG; ++li)
        tmc[li] = tmat[(size_t)(row0 + li) * SEQL + m];

    // ---- scores ----
    float p0v[QG], p1v[QG];
    const bool waveAllMasked = (wv * 64 > lmax) && !anypad;
#pragma unroll
    for (int li = 0; li < QG; ++li) {
        float s0, s1;
        if (waveAllMasked) {
            s0 = NEGV; s1 = NEGV;
        } else {
            const float4* q4 = (const float4*)(Qo + (size_t)(row0 + li) * HDIM);
            s0 = 0.f; s1 = 0.f;
#pragma unroll
            for (int jj = 0; jj < 8; ++jj) {
                float4 qv = q4[jj];
                s0 += kp[4*jj+0]*qv.x + kp[4*jj+1]*qv.y + kp[4*jj+2]*qv.z + kp[4*jj+3]*qv.w;
            }
#pragma unroll
            for (int jj = 8; jj < 16; ++jj) {
                float4 qv = q4[jj];
                s1 += kp[4*jj+0]*qv.x + kp[4*jj+1]*qv.y + kp[4*jj+2]*qv.z + kp[4*jj+3]*qv.w;
            }
            const float* tkrow = Tk + (size_t)(row0 + li) * TKW;
            s0 = (s0 + tkrow[tmc[li]]) * INV_SQRT_HS;
            s1 = (s1 + tkrow[TKC + tmc[li]]) * INV_SQRT_HS;
            const bool masked = (m > l0 + li) || qpad[li];
            s0 = masked ? NEGV : s0;
            s1 = masked ? NEGV : s1;
        }
        p0v[li] = s0; p1v[li] = s1;
    }
    // ---- softmax ----
#pragma unroll
    for (int li = 0; li < QG; ++li) {
        float a0 = p0v[li], a1 = p1v[li];
#pragma unroll
        for (int o = 32; o > 0; o >>= 1) {
            a0 = fmaxf(a0, __shfl_xor(a0, o));
            a1 = fmaxf(a1, __shfl_xor(a1, o));
        }
        if (lane == 0) { redm[li][0][wv] = a0; redm[li][1][wv] = a1; }
    }
    __syncthreads();
#pragma unroll
    for (int li = 0; li < QG; ++li) {
        float m0 = fmaxf(fmaxf(redm[li][0][0], redm[li][0][1]),
                         fmaxf(redm[li][0][2], redm[li][0][3]));
        float m1 = fmaxf(fmaxf(redm[li][1][0], redm[li][1][1]),
                         fmaxf(redm[li][1][2], redm[li][1][3]));
        float e0 = __expf(p0v[li] - m0), e1 = __expf(p1v[li] - m1);
        p0v[li] = e0; p1v[li] = e1;
        float t0 = waveReduceSum(e0), t1 = waveReduceSum(e1);
        if (lane == 0) { reds[li][0][wv] = t0; reds[li][1][wv] = t1; }
    }
    __syncthreads();
#pragma unroll
    for (int li = 0; li < QG; ++li) {
        float sum0 = reds[li][0][0] + reds[li][0][1] + reds[li][0][2] + reds[li][0][3];
        float sum1 = reds[li][1][0] + reds[li][1][1] + reds[li][1][2] + reds[li][1][3];
        float a0 = p0v[li] / sum0;
        float a1 = p1v[li] / sum1;
        A_s[li][0][m] = a0;
        A_s[li][1][m] = a1;
        if (a0 != 0.f) atomicAdd(&Wl[li][0][tmc[li]], a0);
        if (a1 != 0.f) atomicAdd(&Wl[li][1][tmc[li]], a1);
    }
    __syncthreads();

    // ---- output: dense coalesced sweeps ----
    const int hd = lane, chunk = wv;
    const int h = hd >> 5;
    float acc[QG];
#pragma unroll
    for (int li = 0; li < QG; ++li) acc[li] = 0.f;

    const int mend = anypad ? SEQL : (lmax + 1 < SEQL ? lmax + 1 : SEQL);
    for (int mm = chunk; mm < mend; mm += 4) {
        float vp = Vp[(size_t)(b * SEQL + mm) * HDIM + hd];
#pragma unroll
        for (int li = 0; li < QG; ++li)
            acc[li] += A_s[li][h][mm] * vp;
    }
    for (int c = chunk; c < TKC; c += 4) {
        float w0 = Wl[0][h][c], w1 = Wl[1][h][c], w2 = Wl[2][h][c], w3 = Wl[3][h][c];
        if (w0 != 0.f || w1 != 0.f || w2 != 0.f || w3 != 0.f) {
            float tv = tVtab[(size_t)c * HDIM + hd];
            acc[0] += w0 * tv; acc[1] += w1 * tv;
            acc[2] += w2 * tv; acc[3] += w3 * tv;
        }
    }
#pragma unroll
    for (int li = 0; li < QG; ++li) outred[chunk][li][hd] = acc[li];
    __syncthreads();
    {
        const int li = tid >> 6, dcol = tid & 63;
        const int row = row0 + li;
        float o = outred[0][li][dcol] + outred[1][li][dcol]
                + outred[2][li][dcol] + outred[3][li][dcol];
        x2[(size_t)row * HDIM + dcol] = q_in[(size_t)row * HDIM + dcol] + o;
    }
}

// 4 rows/block: LN2 + FFN (transposed weights, coalesced) + residual + keep
// (+ fused final LN on last layer).
__global__ __launch_bounds__(256) void ffn_kernel(
    const float* __restrict__ x2, const int* __restrict__ seqs_data,
    const float* __restrict__ g2, const float* __restrict__ bg2,
    const float* __restrict__ W1T, const float* __restrict__ bb1,
    const float* __restrict__ W2T, const float* __restrict__ bb2,
    const float* __restrict__ lg, const float* __restrict__ lb,
    float* __restrict__ xout, float* __restrict__ dout, int final_ln)
{
    const int w = threadIdx.x >> 6;
    const int t = threadIdx.x & 63;
    const int row = blockIdx.x * 4 + w;
    float x = x2[(size_t)row * HDIM + t];
    float mean = waveReduceSum(x) * (1.f / HDIM);
    float d = x - mean;
    float var = waveReduceSum(d * d) * (1.f / HDIM);
    float s = g2[t] * d / sqrtf(var + LNEPS) + bg2[t];

    __shared__ float ss[4][HDIM];
    __shared__ float hs[4][HDIM];
    ss[w][t] = s;                       // same-wave
    float acc = 0.f;
#pragma unroll 16
    for (int mth = 0; mth < 64; ++mth)
        acc += ss[w][mth] * W1T[mth*64 + t];
    float hval = fmaxf(acc + bb1[t], 0.f);
    hs[w][t] = hval;
    float acc2 = 0.f;
#pragma unroll 16
    for (int mth = 0; mth < 64; ++mth)
        acc2 += hs[w][mth] * W2T[mth*64 + t];
    float y = acc2 + bb2[t] + s;
    if (seqs_data[row] == PADID) y = 0.f;
    if (final_ln) {
        float m2 = waveReduceSum(y) * (1.f / HDIM);
        float dd = y - m2;
        float v2 = waveReduceSum(dd * dd) * (1.f / HDIM);
        dout[(size_t)row * HDIM + t] = lg[t] * dd / sqrtf(v2 + LNEPS) + lb[t];
    } else {
        xout[(size_t)row * HDIM + t] = y;
    }
}

extern "C" void kernel_launch(void* const* d_in, const int* in_sizes, int n_in,
                              void* d_out, int out_size, void* d_ws, size_t ws_size,
                              hipStream_t stream) {
    const int*   seqs_data = (const int*)d_in[0];
    const float* seqs      = (const float*)d_in[1];
    const int*   positions = (const int*)d_in[2];
    const int*   tmat      = (const int*)d_in[3];
    const float* apK       = (const float*)d_in[4];
    const float* apV       = (const float*)d_in[5];
    const float* tKtab     = (const float*)d_in[6];
    const float* tVtab     = (const float*)d_in[7];
    const float* Qw = (const float*)d_in[8];
    const float* Qb = (const float*)d_in[9];
    const float* Kw = (const float*)d_in[10];
    const float* Kb = (const float*)d_in[11];
    const float* Vw = (const float*)d_in[12];
    const float* Vb = (const float*)d_in[13];
    const float* g1 = (const float*)d_in[14];
    const float* b1 = (const float*)d_in[15];
    const float* g2 = (const float*)d_in[16];
    const float* b2 = (const float*)d_in[17];
    const float* W1 = (const float*)d_in[18];
    const float* fb1 = (const float*)d_in[19];
    const float* W2 = (const float*)d_in[20];
    const float* fb2 = (const float*)d_in[21];
    const float* lastg = (const float*)d_in[22];
    const float* lastb = (const float*)d_in[23];

    const size_t N = (size_t)BATCH * SEQL * HDIM;   // 262144
    float* ws    = (float*)d_ws;
    float* x     = ws;
    float* q_in  = ws + 1 * N;
    float* Qo    = ws + 2 * N;
    float* Vp    = ws + 3 * N;
    float* KpT   = ws + 4 * N;
    float* Tk    = ws + 5 * N;                        // 4096*514
    float* wtbase = ws + 5 * N + (size_t)4096 * TKW;
    float* QwT = wtbase;
    float* KwT = wtbase + 8192;
    float* VwT = wtbase + 16384;
    float* W1T = wtbase + 24576;
    float* W2T = wtbase + 32768;
    float* tKtabT = wtbase + 40960;                   // 64*260

    const int rows = BATCH * SEQL;   // 4096

    setup_kernel<<<15, 256, 0, stream>>>(Qw, Kw, Vw, W1, W2, tKtab,
                                         QwT, KwT, VwT, W1T, W2T, tKtabT);

    for (int i = 0; i < NBLK; ++i) {
        const float* xin = (i == 0) ? seqs : x;
        prep_kernel<<<rows / 4, 256, 0, stream>>>(
            xin, seqs_data, positions,
            QwT + (size_t)i * 4096, Qb + (size_t)i * HDIM,
            KwT + (size_t)i * 4096, Kb + (size_t)i * HDIM,
            VwT + (size_t)i * 4096, Vb + (size_t)i * HDIM,
            g1 + (size_t)i * HDIM, b1 + (size_t)i * HDIM,
            apK, apV, q_in, Qo, KpT, Vp, (i == 0) ? 1 : 0);
        tk_kernel<<<rows / 8, 256, 0, stream>>>(Qo, tKtabT, Tk);
        attn_kernel<<<rows / QG, 256, 0, stream>>>(
            Qo, KpT, Vp, q_in, Tk, seqs_data, tmat, tVtab, x);
        ffn_kernel<<<rows / 4, 256, 0, stream>>>(
            x, seqs_data, g2 + (size_t)i * HDIM, b2 + (size_t)i * HDIM,
            W1T + (size_t)i * 4096, fb1 + (size_t)i * HDIM,
            W2T + (size_t)i * 4096, fb2 + (size_t)i * HDIM,
            lastg, lastb, x, (float*)d_out, (i == NBLK - 1) ? 1 : 0);
    }
}

// Round 6
// 206.776 us; speedup vs baseline: 2.1037x; 1.3292x over previous
//
#include <hip/hip_runtime.h>
#include <math.h>

#define BATCH 16
#define SEQL  256
#define HDIM  64
#define NBLK  2
#define PADID 49999
#define NEGV  -4294967295.0f
#define LNEPS 1e-8f
#define INV_SQRT_HS 0.17677669529663687f
#define TKC   257
#define TKTLD 260              // padded leading dim of tKtabT / Tk tiles
#define QG    4                // queries per attn block

__device__ __forceinline__ float waveReduceSum(float v) {
#pragma unroll
    for (int o = 32; o > 0; o >>= 1) v += __shfl_xor(v, o);
    return v;
}

// One-shot transposes: 10 64x64 weight matrices + tKtab (257x64 -> 64x260).
__global__ __launch_bounds__(256) void setup_kernel(
    const float* __restrict__ Qw, const float* __restrict__ Kw,
    const float* __restrict__ Vw, const float* __restrict__ W1,
    const float* __restrict__ W2, const float* __restrict__ tKtab,
    float* __restrict__ QwT, float* __restrict__ KwT, float* __restrict__ VwT,
    float* __restrict__ W1T, float* __restrict__ W2T, float* __restrict__ tKtabT)
{
    __shared__ float tile[64][65];
    const int tid = threadIdx.x;
    const int blk = blockIdx.x;
    if (blk < 10) {
        const float* srcs[10] = {Qw, Qw+4096, Kw, Kw+4096, Vw, Vw+4096,
                                 W1, W1+4096, W2, W2+4096};
        float*       dsts[10] = {QwT, QwT+4096, KwT, KwT+4096, VwT, VwT+4096,
                                 W1T, W1T+4096, W2T, W2T+4096};
        const float* s = srcs[blk];
        float*       d = dsts[blk];
        for (int p = 0; p < 16; ++p) {
            int r = p*4 + (tid>>6), c = tid&63;
            tile[r][c] = s[r*64 + c];
        }
        __syncthreads();
        for (int p = 0; p < 16; ++p) {
            int mth = p*4 + (tid>>6), t = tid&63;
            d[mth*64 + t] = tile[t][mth];
        }
    } else {
        const int s0 = (blk - 10) * 64;
        const int nrows = min(64, TKC - s0);
        for (int p = 0; p < 16; ++p) {
            int rr = p*4 + (tid>>6), c = tid&63;
            if (rr < nrows) tile[rr][c] = tKtab[(size_t)(s0+rr)*64 + c];
        }
        __syncthreads();
        for (int p = 0; p < 16; ++p) {
            int dd = p*4 + (tid>>6), cc = tid&63;
            if (cc < nrows) tKtabT[dd*TKTLD + s0 + cc] = tile[cc][dd];
        }
    }
}

// Layer-0 prep: 4 rows/block, LN1 + Q/Kp/Vp projections (coalesced weights).
__global__ __launch_bounds__(256) void prep_kernel(
    const float* __restrict__ xin, const int* __restrict__ seqs_data,
    const int* __restrict__ positions,
    const float* __restrict__ QwT, const float* __restrict__ Qb,
    const float* __restrict__ KwT, const float* __restrict__ Kb,
    const float* __restrict__ VwT, const float* __restrict__ Vb,
    const float* __restrict__ g1, const float* __restrict__ b1,
    const float* __restrict__ apK, const float* __restrict__ apV,
    float* __restrict__ q_in, float* __restrict__ Qo,
    float* __restrict__ KpT, float* __restrict__ Vp)
{
    const int w = threadIdx.x >> 6;
    const int t = threadIdx.x & 63;
    const int row0 = blockIdx.x * 4;
    const int row = row0 + w;
    float x = xin[(size_t)row * HDIM + t];
    if (seqs_data[row] == PADID) x = 0.f;

    float mean = waveReduceSum(x) * (1.f / HDIM);
    float d = x - mean;
    float var = waveReduceSum(d * d) * (1.f / HDIM);
    float q = g1[t] * d / sqrtf(var + LNEPS) + b1[t];

    __shared__ float xs[4][HDIM];
    __shared__ float qs[4][HDIM];
    __shared__ float kx[HDIM][5];
    xs[w][t] = x; qs[w][t] = q;            // same-wave write/read
    q_in[(size_t)row * HDIM + t] = q;

    int pos = positions[row];
    float aK = pos ? apK[(size_t)pos * HDIM + t] : 0.f;
    float aV = pos ? apV[(size_t)pos * HDIM + t] : 0.f;

    float aq = 0.f, ak = 0.f, av = 0.f;
#pragma unroll 16
    for (int mth = 0; mth < 64; ++mth) {
        float qm = qs[w][mth], xm = xs[w][mth];
        aq += qm * QwT[mth*64 + t];
        ak += xm * KwT[mth*64 + t];
        av += xm * VwT[mth*64 + t];
    }
    Qo[(size_t)row * HDIM + t] = aq + Qb[t];
    Vp[(size_t)row * HDIM + t] = av + Vb[t] + aV;
    kx[t][w] = ak + Kb[t] + aK;
    __syncthreads();
    const int f = threadIdx.x >> 2, j = threadIdx.x & 3;
    KpT[(size_t)f * 4096 + row0 + j] = kx[f][j];
}

// Attention, QG=4 queries/block, Tk computed in-LDS, pipelined dense sweeps.
__global__ __launch_bounds__(256) void attn_kernel(
    const float* __restrict__ Qo, const float* __restrict__ KpT,
    const float* __restrict__ Vp, const float* __restrict__ q_in,
    const int* __restrict__ seqs_data, const int* __restrict__ tmat,
    const float* __restrict__ tVtab, const float* __restrict__ tKtabT,
    float* __restrict__ x2)
{
    // XCD swizzle: co-locate the 64 blocks sharing a batch on one XCD.
    const int hw  = blockIdx.x;
    const int blk = (hw & 7) * 128 + (hw >> 3);
    const int b   = blk >> 6;
    const int l0  = (blk & 63) << 2;
    const int row0 = b * SEQL + l0;
    const int tid = threadIdx.x;
    const int m = tid;
    const int lane = tid & 63, wv = tid >> 6;

    __shared__ float qs_l[QG][HDIM];
    __shared__ float Tk_l[QG][2][TKTLD];
    __shared__ float A_s[QG][2][SEQL];
    __shared__ float Wl[QG][2][TKTLD];
    __shared__ float outred[4][QG][HDIM];
    __shared__ float redm[QG][2][4];
    __shared__ float reds[QG][2][4];

    for (int k = tid; k < QG*2*TKTLD; k += 256) ((float*)Wl)[k] = 0.f;
    qs_l[tid >> 6][tid & 63] = Qo[(size_t)(row0 + (tid >> 6)) * HDIM + (tid & 63)];
    __syncthreads();

    // ---- Tk tile in LDS: Tk_l[r][h][c] = Q[r,h] . tKtab[c,h] ----
    for (int c = tid; c < TKC; c += 256) {
        float a00 = 0.f, a10 = 0.f, a20 = 0.f, a30 = 0.f;
        float a01 = 0.f, a11 = 0.f, a21 = 0.f, a31 = 0.f;
#pragma unroll 8
        for (int dd = 0; dd < 32; ++dd) {
            float tt = tKtabT[dd*TKTLD + c];
            a00 += tt * qs_l[0][dd]; a10 += tt * qs_l[1][dd];
            a20 += tt * qs_l[2][dd]; a30 += tt * qs_l[3][dd];
        }
#pragma unroll 8
        for (int dd = 32; dd < 64; ++dd) {
            float tt = tKtabT[dd*TKTLD + c];
            a01 += tt * qs_l[0][dd]; a11 += tt * qs_l[1][dd];
            a21 += tt * qs_l[2][dd]; a31 += tt * qs_l[3][dd];
        }
        Tk_l[0][0][c] = a00; Tk_l[1][0][c] = a10; Tk_l[2][0][c] = a20; Tk_l[3][0][c] = a30;
        Tk_l[0][1][c] = a01; Tk_l[1][1][c] = a11; Tk_l[2][1][c] = a21; Tk_l[3][1][c] = a31;
    }

    bool qpad[QG]; bool anypad = false;
#pragma unroll
    for (int li = 0; li < QG; ++li) {
        qpad[li] = (seqs_data[row0 + li] == PADID);
        anypad |= qpad[li];
    }
    const int lmax = l0 + QG - 1;

    float kp[64];
    if ((m <= lmax) || anypad) {
#pragma unroll
        for (int dd = 0; dd < 64; ++dd)
            kp[dd] = KpT[(size_t)dd * 4096 + b * SEQL + m];   // coalesced
    } else {
#pragma unroll
        for (int dd = 0; dd < 64; ++dd) kp[dd] = 0.f;
    }
    int tmc[QG];
#pragma unroll
    for (int li = 0; li < QG; ++li)
        tmc[li] = tmat[(size_t)(row0 + li) * SEQL + m];
    __syncthreads();   // Tk_l ready

    // ---- scores ----
    float p0v[QG], p1v[QG];
    const bool waveAllMasked = (wv * 64 > lmax) && !anypad;
#pragma unroll
    for (int li = 0; li < QG; ++li) {
        float s0, s1;
        if (waveAllMasked) {
            s0 = NEGV; s1 = NEGV;
        } else {
            const float4* q4 = (const float4*)&qs_l[li][0];
            s0 = 0.f; s1 = 0.f;
#pragma unroll
            for (int jj = 0; jj < 8; ++jj) {
                float4 qv = q4[jj];
                s0 += kp[4*jj+0]*qv.x + kp[4*jj+1]*qv.y + kp[4*jj+2]*qv.z + kp[4*jj+3]*qv.w;
            }
#pragma unroll
            for (int jj = 8; jj < 16; ++jj) {
                float4 qv = q4[jj];
                s1 += kp[4*jj+0]*qv.x + kp[4*jj+1]*qv.y + kp[4*jj+2]*qv.z + kp[4*jj+3]*qv.w;
            }
            s0 = (s0 + Tk_l[li][0][tmc[li]]) * INV_SQRT_HS;
            s1 = (s1 + Tk_l[li][1][tmc[li]]) * INV_SQRT_HS;
            const bool masked = (m > l0 + li) || qpad[li];
            s0 = masked ? NEGV : s0;
            s1 = masked ? NEGV : s1;
        }
        p0v[li] = s0; p1v[li] = s1;
    }
    // ---- softmax ----
#pragma unroll
    for (int li = 0; li < QG; ++li) {
        float a0 = p0v[li], a1 = p1v[li];
#pragma unroll
        for (int o = 32; o > 0; o >>= 1) {
            a0 = fmaxf(a0, __shfl_xor(a0, o));
            a1 = fmaxf(a1, __shfl_xor(a1, o));
        }
        if (lane == 0) { redm[li][0][wv] = a0; redm[li][1][wv] = a1; }
    }
    __syncthreads();
#pragma unroll
    for (int li = 0; li < QG; ++li) {
        float m0 = fmaxf(fmaxf(redm[li][0][0], redm[li][0][1]),
                         fmaxf(redm[li][0][2], redm[li][0][3]));
        float m1 = fmaxf(fmaxf(redm[li][1][0], redm[li][1][1]),
                         fmaxf(redm[li][1][2], redm[li][1][3]));
        float e0 = __expf(p0v[li] - m0), e1 = __expf(p1v[li] - m1);
        p0v[li] = e0; p1v[li] = e1;
        float t0 = waveReduceSum(e0), t1 = waveReduceSum(e1);
        if (lane == 0) { reds[li][0][wv] = t0; reds[li][1][wv] = t1; }
    }
    __syncthreads();
#pragma unroll
    for (int li = 0; li < QG; ++li) {
        float sum0 = reds[li][0][0] + reds[li][0][1] + reds[li][0][2] + reds[li][0][3];
        float sum1 = reds[li][1][0] + reds[li][1][1] + reds[li][1][2] + reds[li][1][3];
        float a0 = p0v[li] / sum0;
        float a1 = p1v[li] / sum1;
        A_s[li][0][m] = a0;
        A_s[li][1][m] = a1;
        if (a0 != 0.f) atomicAdd(&Wl[li][0][tmc[li]], a0);
        if (a1 != 0.f) atomicAdd(&Wl[li][1][tmc[li]], a1);
    }
    __syncthreads();

    // ---- output: dense sweeps, 4 loads in flight ----
    const int hd = lane, chunk = wv;
    const int h = hd >> 5;
    float acc0 = 0.f, acc1 = 0.f, acc2 = 0.f, acc3 = 0.f;

    const int mend = anypad ? SEQL : (lmax + 1 < SEQL ? lmax + 1 : SEQL);
    const float* vpb = Vp + (size_t)(b * SEQL) * HDIM + hd;
    int mm = chunk;
    for (; mm + 12 < mend; mm += 16) {
        float v0 = vpb[(size_t)(mm)    * HDIM];
        float v1 = vpb[(size_t)(mm+4)  * HDIM];
        float v2 = vpb[(size_t)(mm+8)  * HDIM];
        float v3 = vpb[(size_t)(mm+12) * HDIM];
        acc0 += A_s[0][h][mm]*v0 + A_s[0][h][mm+4]*v1 + A_s[0][h][mm+8]*v2 + A_s[0][h][mm+12]*v3;
        acc1 += A_s[1][h][mm]*v0 + A_s[1][h][mm+4]*v1 + A_s[1][h][mm+8]*v2 + A_s[1][h][mm+12]*v3;
        acc2 += A_s[2][h][mm]*v0 + A_s[2][h][mm+4]*v1 + A_s[2][h][mm+8]*v2 + A_s[2][h][mm+12]*v3;
        acc3 += A_s[3][h][mm]*v0 + A_s[3][h][mm+4]*v1 + A_s[3][h][mm+8]*v2 + A_s[3][h][mm+12]*v3;
    }
    for (; mm < mend; mm += 4) {
        float vp = vpb[(size_t)mm * HDIM];
        acc0 += A_s[0][h][mm]*vp; acc1 += A_s[1][h][mm]*vp;
        acc2 += A_s[2][h][mm]*vp; acc3 += A_s[3][h][mm]*vp;
    }
    const float* tvb = tVtab + hd;
    int c = chunk;
    for (; c + 12 < TKC; c += 16) {
        float t0 = tvb[(size_t)(c)    * HDIM];
        float t1 = tvb[(size_t)(c+4)  * HDIM];
        float t2 = tvb[(size_t)(c+8)  * HDIM];
        float t3 = tvb[(size_t)(c+12) * HDIM];
        acc0 += Wl[0][h][c]*t0 + Wl[0][h][c+4]*t1 + Wl[0][h][c+8]*t2 + Wl[0][h][c+12]*t3;
        acc1 += Wl[1][h][c]*t0 + Wl[1][h][c+4]*t1 + Wl[1][h][c+8]*t2 + Wl[1][h][c+12]*t3;
        acc2 += Wl[2][h][c]*t0 + Wl[2][h][c+4]*t1 + Wl[2][h][c+8]*t2 + Wl[2][h][c+12]*t3;
        acc3 += Wl[3][h][c]*t0 + Wl[3][h][c+4]*t1 + Wl[3][h][c+8]*t2 + Wl[3][h][c+12]*t3;
    }
    for (; c < TKC; c += 4) {
        float tv = tvb[(size_t)c * HDIM];
        acc0 += Wl[0][h][c]*tv; acc1 += Wl[1][h][c]*tv;
        acc2 += Wl[2][h][c]*tv; acc3 += Wl[3][h][c]*tv;
    }
    outred[chunk][0][hd] = acc0;
    outred[chunk][1][hd] = acc1;
    outred[chunk][2][hd] = acc2;
    outred[chunk][3][hd] = acc3;
    __syncthreads();
    {
        const int li = tid >> 6, dcol = tid & 63;
        const int row = row0 + li;
        float o = outred[0][li][dcol] + outred[1][li][dcol]
                + outred[2][li][dcol] + outred[3][li][dcol];
        x2[(size_t)row * HDIM + dcol] = q_in[(size_t)row * HDIM + dcol] + o;
    }
}

// Fused: LN2 + FFN + residual + keep (layer i)  ->  LN1 + QKV prep (layer i+1).
__global__ __launch_bounds__(256) void ffnprep_kernel(
    const float* __restrict__ x2, const int* __restrict__ seqs_data,
    const int* __restrict__ positions,
    const float* __restrict__ g2, const float* __restrict__ bg2,
    const float* __restrict__ W1T, const float* __restrict__ bb1,
    const float* __restrict__ W2T, const float* __restrict__ bb2,
    const float* __restrict__ g1n, const float* __restrict__ b1n,
    const float* __restrict__ QwT, const float* __restrict__ Qb,
    const float* __restrict__ KwT, const float* __restrict__ Kb,
    const float* __restrict__ VwT, const float* __restrict__ Vb,
    const float* __restrict__ apK, const float* __restrict__ apV,
    float* __restrict__ q_in, float* __restrict__ Qo,
    float* __restrict__ KpT, float* __restrict__ Vp)
{
    const int w = threadIdx.x >> 6;
    const int t = threadIdx.x & 63;
    const int row0 = blockIdx.x * 4;
    const int row = row0 + w;
    float x = x2[(size_t)row * HDIM + t];
    float mean = waveReduceSum(x) * (1.f / HDIM);
    float d = x - mean;
    float var = waveReduceSum(d * d) * (1.f / HDIM);
    float s = g2[t] * d / sqrtf(var + LNEPS) + bg2[t];

    __shared__ float ss[4][HDIM];
    __shared__ float hs[4][HDIM];
    __shared__ float kx[HDIM][5];
    ss[w][t] = s;
    float acc = 0.f;
#pragma unroll 16
    for (int mth = 0; mth < 64; ++mth)
        acc += ss[w][mth] * W1T[mth*64 + t];
    float hval = fmaxf(acc + bb1[t], 0.f);
    hs[w][t] = hval;
    float acc2 = 0.f;
#pragma unroll 16
    for (int mth = 0; mth < 64; ++mth)
        acc2 += hs[w][mth] * W2T[mth*64 + t];
    float y = acc2 + bb2[t] + s;
    if (seqs_data[row] == PADID) y = 0.f;

    // ---- prep of next layer on y ----
    float mean2 = waveReduceSum(y) * (1.f / HDIM);
    float d2 = y - mean2;
    float var2 = waveReduceSum(d2 * d2) * (1.f / HDIM);
    float q = g1n[t] * d2 / sqrtf(var2 + LNEPS) + b1n[t];

    ss[w][t] = y;   // reuse as xs
    hs[w][t] = q;   // reuse as qs
    q_in[(size_t)row * HDIM + t] = q;

    int pos = positions[row];
    float aK = pos ? apK[(size_t)pos * HDIM + t] : 0.f;
    float aV = pos ? apV[(size_t)pos * HDIM + t] : 0.f;

    float aq = 0.f, ak = 0.f, av = 0.f;
#pragma unroll 16
    for (int mth = 0; mth < 64; ++mth) {
        float qm = hs[w][mth], ym = ss[w][mth];
        aq += qm * QwT[mth*64 + t];
        ak += ym * KwT[mth*64 + t];
        av += ym * VwT[mth*64 + t];
    }
    Qo[(size_t)row * HDIM + t] = aq + Qb[t];
    Vp[(size_t)row * HDIM + t] = av + Vb[t] + aV;
    kx[t][w] = ak + Kb[t] + aK;
    __syncthreads();
    const int f = threadIdx.x >> 2, j = threadIdx.x & 3;
    KpT[(size_t)f * 4096 + row0 + j] = kx[f][j];
}

// Final: LN2 + FFN + residual + keep + last LayerNorm -> d_out.
__global__ __launch_bounds__(256) void ffnfinal_kernel(
    const float* __restrict__ x2, const int* __restrict__ seqs_data,
    const float* __restrict__ g2, const float* __restrict__ bg2,
    const float* __restrict__ W1T, const float* __restrict__ bb1,
    const float* __restrict__ W2T, const float* __restrict__ bb2,
    const float* __restrict__ lg, const float* __restrict__ lb,
    float* __restrict__ dout)
{
    const int w = threadIdx.x >> 6;
    const int t = threadIdx.x & 63;
    const int row = blockIdx.x * 4 + w;
    float x = x2[(size_t)row * HDIM + t];
    float mean = waveReduceSum(x) * (1.f / HDIM);
    float d = x - mean;
    float var = waveReduceSum(d * d) * (1.f / HDIM);
    float s = g2[t] * d / sqrtf(var + LNEPS) + bg2[t];

    __shared__ float ss[4][HDIM];
    __shared__ float hs[4][HDIM];
    ss[w][t] = s;
    float acc = 0.f;
#pragma unroll 16
    for (int mth = 0; mth < 64; ++mth)
        acc += ss[w][mth] * W1T[mth*64 + t];
    float hval = fmaxf(acc + bb1[t], 0.f);
    hs[w][t] = hval;
    float acc2 = 0.f;
#pragma unroll 16
    for (int mth = 0; mth < 64; ++mth)
        acc2 += hs[w][mth] * W2T[mth*64 + t];
    float y = acc2 + bb2[t] + s;
    if (seqs_data[row] == PADID) y = 0.f;
    float m2 = waveReduceSum(y) * (1.f / HDIM);
    float dd = y - m2;
    float v2 = waveReduceSum(dd * dd) * (1.f / HDIM);
    dout[(size_t)row * HDIM + t] = lg[t] * dd / sqrtf(v2 + LNEPS) + lb[t];
}

extern "C" void kernel_launch(void* const* d_in, const int* in_sizes, int n_in,
                              void* d_out, int out_size, void* d_ws, size_t ws_size,
                              hipStream_t stream) {
    const int*   seqs_data = (const int*)d_in[0];
    const float* seqs      = (const float*)d_in[1];
    const int*   positions = (const int*)d_in[2];
    const int*   tmat      = (const int*)d_in[3];
    const float* apK       = (const float*)d_in[4];
    const float* apV       = (const float*)d_in[5];
    const float* tKtab     = (const float*)d_in[6];
    const float* tVtab     = (const float*)d_in[7];
    const float* Qw = (const float*)d_in[8];
    const float* Qb = (const float*)d_in[9];
    const float* Kw = (const float*)d_in[10];
    const float* Kb = (const float*)d_in[11];
    const float* Vw = (const float*)d_in[12];
    const float* Vb = (const float*)d_in[13];
    const float* g1 = (const float*)d_in[14];
    const float* b1 = (const float*)d_in[15];
    const float* g2 = (const float*)d_in[16];
    const float* b2 = (const float*)d_in[17];
    const float* W1 = (const float*)d_in[18];
    const float* fb1 = (const float*)d_in[19];
    const float* W2 = (const float*)d_in[20];
    const float* fb2 = (const float*)d_in[21];
    const float* lastg = (const float*)d_in[22];
    const float* lastb = (const float*)d_in[23];

    const size_t N = (size_t)BATCH * SEQL * HDIM;   // 262144
    float* ws    = (float*)d_ws;
    float* x     = ws;           // attn output x2
    float* q_in  = ws + 1 * N;
    float* Qo    = ws + 2 * N;
    float* Vp    = ws + 3 * N;
    float* KpT   = ws + 4 * N;
    float* wtbase = ws + 5 * N;
    float* QwT = wtbase;                 // 2 layers x 4096
    float* KwT = wtbase + 8192;
    float* VwT = wtbase + 16384;
    float* W1T = wtbase + 24576;
    float* W2T = wtbase + 32768;
    float* tKtabT = wtbase + 40960;      // 64*260

    const int rows = BATCH * SEQL;   // 4096

    setup_kernel<<<15, 256, 0, stream>>>(Qw, Kw, Vw, W1, W2, tKtab,
                                         QwT, KwT, VwT, W1T, W2T, tKtabT);

    prep_kernel<<<rows / 4, 256, 0, stream>>>(
        seqs, seqs_data, positions,
        QwT, Qb, KwT, Kb, VwT, Vb, g1, b1,
        apK, apV, q_in, Qo, KpT, Vp);

    attn_kernel<<<rows / QG, 256, 0, stream>>>(
        Qo, KpT, Vp, q_in, seqs_data, tmat, tVtab, tKtabT, x);

    ffnprep_kernel<<<rows / 4, 256, 0, stream>>>(
        x, seqs_data, positions,
        g2, b2, W1T, fb1, W2T, fb2,
        g1 + HDIM, b1 + HDIM,
        QwT + 4096, Qb + HDIM, KwT + 4096, Kb + HDIM, VwT + 4096, Vb + HDIM,
        apK, apV, q_in, Qo, KpT, Vp);

    attn_kernel<<<rows / QG, 256, 0, stream>>>(
        Qo, KpT, Vp, q_in, seqs_data, tmat, tVtab, tKtabT, x);

    ffnfinal_kernel<<<rows / 4, 256, 0, stream>>>(
        x, seqs_data,
        g2 + HDIM, b2 + HDIM, W1T + 4096, fb1 + HDIM, W2T + 4096, fb2 + HDIM,
        lastg, lastb, (float*)d_out);
}

// Round 7
// 205.938 us; speedup vs baseline: 2.1123x; 1.0041x over previous
//
#include <hip/hip_runtime.h>
#include <math.h>

#define BATCH 16
#define SEQL  256
#define HDIM  64
#define NBLK  2
#define PADID 49999
#define NEGV  -4294967295.0f
#define LNEPS 1e-8f
#define INV_SQRT_HS 0.17677669529663687f
#define TKC   257
#define TKTLD 260              // padded leading dim of tKtabT / Tk tiles
#define QG    4                // queries per attn block

__device__ __forceinline__ float waveReduceSum(float v) {
#pragma unroll
    for (int o = 32; o > 0; o >>= 1) v += __shfl_xor(v, o);
    return v;
}

// One-shot transposes: 10 64x64 weight matrices + tKtab (257x64 -> 64x260).
__global__ __launch_bounds__(256) void setup_kernel(
    const float* __restrict__ Qw, const float* __restrict__ Kw,
    const float* __restrict__ Vw, const float* __restrict__ W1,
    const float* __restrict__ W2, const float* __restrict__ tKtab,
    float* __restrict__ QwT, float* __restrict__ KwT, float* __restrict__ VwT,
    float* __restrict__ W1T, float* __restrict__ W2T, float* __restrict__ tKtabT)
{
    __shared__ float tile[64][65];
    const int tid = threadIdx.x;
    const int blk = blockIdx.x;
    if (blk < 10) {
        const float* srcs[10] = {Qw, Qw+4096, Kw, Kw+4096, Vw, Vw+4096,
                                 W1, W1+4096, W2, W2+4096};
        float*       dsts[10] = {QwT, QwT+4096, KwT, KwT+4096, VwT, VwT+4096,
                                 W1T, W1T+4096, W2T, W2T+4096};
        const float* s = srcs[blk];
        float*       d = dsts[blk];
        for (int p = 0; p < 16; ++p) {
            int r = p*4 + (tid>>6), c = tid&63;
            tile[r][c] = s[r*64 + c];
        }
        __syncthreads();
        for (int p = 0; p < 16; ++p) {
            int mth = p*4 + (tid>>6), t = tid&63;
            d[mth*64 + t] = tile[t][mth];
        }
    } else {
        const int s0 = (blk - 10) * 64;
        const int nrows = min(64, TKC - s0);
        for (int p = 0; p < 16; ++p) {
            int rr = p*4 + (tid>>6), c = tid&63;
            if (rr < nrows) tile[rr][c] = tKtab[(size_t)(s0+rr)*64 + c];
        }
        __syncthreads();
        for (int p = 0; p < 16; ++p) {
            int dd = p*4 + (tid>>6), cc = tid&63;
            if (cc < nrows) tKtabT[dd*TKTLD + s0 + cc] = tile[cc][dd];
        }
    }
}

// Layer-0 prep: 4 rows/block, LN1 + Q/Kp/Vp projections (coalesced weights).
__global__ __launch_bounds__(256) void prep_kernel(
    const float* __restrict__ xin, const int* __restrict__ seqs_data,
    const int* __restrict__ positions,
    const float* __restrict__ QwT, const float* __restrict__ Qb,
    const float* __restrict__ KwT, const float* __restrict__ Kb,
    const float* __restrict__ VwT, const float* __restrict__ Vb,
    const float* __restrict__ g1, const float* __restrict__ b1,
    const float* __restrict__ apK, const float* __restrict__ apV,
    float* __restrict__ q_in, float* __restrict__ Qo,
    float* __restrict__ KpT, float* __restrict__ Vp)
{
    const int w = threadIdx.x >> 6;
    const int t = threadIdx.x & 63;
    const int row0 = blockIdx.x * 4;
    const int row = row0 + w;
    float x = xin[(size_t)row * HDIM + t];
    if (seqs_data[row] == PADID) x = 0.f;

    float mean = waveReduceSum(x) * (1.f / HDIM);
    float d = x - mean;
    float var = waveReduceSum(d * d) * (1.f / HDIM);
    float q = g1[t] * d / sqrtf(var + LNEPS) + b1[t];

    __shared__ float xs[4][HDIM];
    __shared__ float qs[4][HDIM];
    __shared__ float kx[HDIM][5];
    xs[w][t] = x; qs[w][t] = q;            // same-wave write/read
    q_in[(size_t)row * HDIM + t] = q;

    int pos = positions[row];
    float aK = pos ? apK[(size_t)pos * HDIM + t] : 0.f;
    float aV = pos ? apV[(size_t)pos * HDIM + t] : 0.f;

    float aq = 0.f, ak = 0.f, av = 0.f;
#pragma unroll 16
    for (int mth = 0; mth < 64; ++mth) {
        float qm = qs[w][mth], xm = xs[w][mth];
        aq += qm * QwT[mth*64 + t];
        ak += xm * KwT[mth*64 + t];
        av += xm * VwT[mth*64 + t];
    }
    Qo[(size_t)row * HDIM + t] = aq + Qb[t];
    Vp[(size_t)row * HDIM + t] = av + Vb[t] + aV;
    kx[t][w] = ak + Kb[t] + aK;
    __syncthreads();
    const int f = threadIdx.x >> 2, j = threadIdx.x & 3;
    KpT[(size_t)f * 4096 + row0 + j] = kx[f][j];
}

// Attention: 512 threads, thread=(m, h).  Tk tile in one LDS pass; scores
// dd-outer (each KpT value loaded once, 4 FMAs); batched softmax; histogram
// scatter for the time-V term; 8-chunk pipelined dense output sweeps.
__global__ __launch_bounds__(512) void attn_kernel(
    const float* __restrict__ Qo, const float* __restrict__ KpT,
    const float* __restrict__ Vp, const float* __restrict__ q_in,
    const int* __restrict__ seqs_data, const int* __restrict__ tmat,
    const float* __restrict__ tVtab, const float* __restrict__ tKtabT,
    float* __restrict__ x2)
{
    // XCD swizzle: co-locate the 64 blocks sharing a batch on one XCD.
    const int hw  = blockIdx.x;
    const int blk = (hw & 7) * 128 + (hw >> 3);
    const int b   = blk >> 6;
    const int l0  = (blk & 63) << 2;
    const int row0 = b * SEQL + l0;
    const int tid = threadIdx.x;
    const int m   = tid & 255;
    const int h   = tid >> 8;          // head of this thread
    const int lane = tid & 63;
    const int wv  = tid >> 6;          // 0..7
    const int mw  = wv & 3;            // m-wave index within head

    __shared__ float qs_l[QG][HDIM];
    __shared__ float Tk_l[QG][2][TKTLD];
    __shared__ float A_s[QG][2][SEQL];
    __shared__ float Wl[QG][2][TKTLD];
    __shared__ float outred[8][QG][HDIM];
    __shared__ float redm[QG][2][4];
    __shared__ float reds[QG][2][4];

    for (int k = tid; k < QG*2*TKTLD; k += 512) ((float*)Wl)[k] = 0.f;
    if (tid < QG*HDIM)
        qs_l[tid >> 6][tid & 63] = Qo[(size_t)(row0 + (tid >> 6)) * HDIM + (tid & 63)];

    bool qpad[QG]; bool anypad = false;
#pragma unroll
    for (int li = 0; li < QG; ++li) {
        qpad[li] = (seqs_data[row0 + li] == PADID);
        anypad |= qpad[li];
    }
    const int lmax = l0 + QG - 1;
    int tmc[QG];
#pragma unroll
    for (int li = 0; li < QG; ++li)
        tmc[li] = tmat[(size_t)(row0 + li) * SEQL + m];
    __syncthreads();   // qs_l ready

    // ---- Tk tile: Tk_l[li][hh][c] = Q[li,hh] . tKtab[c,hh]; 257 threads ----
    if (tid < TKC) {
        const int c = tid;
        float a00=0.f,a10=0.f,a20=0.f,a30=0.f, a01=0.f,a11=0.f,a21=0.f,a31=0.f;
#pragma unroll 8
        for (int dd = 0; dd < 32; ++dd) {
            float tt = tKtabT[dd*TKTLD + c];
            a00 += tt * qs_l[0][dd]; a10 += tt * qs_l[1][dd];
            a20 += tt * qs_l[2][dd]; a30 += tt * qs_l[3][dd];
        }
#pragma unroll 8
        for (int dd = 32; dd < 64; ++dd) {
            float tt = tKtabT[dd*TKTLD + c];
            a01 += tt * qs_l[0][dd]; a11 += tt * qs_l[1][dd];
            a21 += tt * qs_l[2][dd]; a31 += tt * qs_l[3][dd];
        }
        Tk_l[0][0][c]=a00; Tk_l[1][0][c]=a10; Tk_l[2][0][c]=a20; Tk_l[3][0][c]=a30;
        Tk_l[0][1][c]=a01; Tk_l[1][1][c]=a11; Tk_l[2][1][c]=a21; Tk_l[3][1][c]=a31;
    }
    __syncthreads();   // Tk_l ready

    // ---- scores: dd-outer, each KpT value loaded once ----
    float sv[QG];
    const bool waveAllMasked = (mw * 64 > lmax) && !anypad;
    if (waveAllMasked) {
#pragma unroll
        for (int li = 0; li < QG; ++li) sv[li] = NEGV;
    } else {
        float s0=0.f, s1=0.f, s2=0.f, s3=0.f;
        const float* kpb = KpT + (size_t)(h*32) * 4096 + (size_t)b * SEQL + m;
        const float* q0 = &qs_l[0][h*32];
        const float* q1 = &qs_l[1][h*32];
        const float* q2 = &qs_l[2][h*32];
        const float* q3 = &qs_l[3][h*32];
#pragma unroll 8
        for (int dd = 0; dd < 32; ++dd) {
            float kv = kpb[(size_t)dd * 4096];
            s0 += kv * q0[dd]; s1 += kv * q1[dd];
            s2 += kv * q2[dd]; s3 += kv * q3[dd];
        }
        float sarr[QG] = {s0, s1, s2, s3};
#pragma unroll
        for (int li = 0; li < QG; ++li) {
            float s = (sarr[li] + Tk_l[li][h][tmc[li]]) * INV_SQRT_HS;
            const bool masked = (m > l0 + li) || qpad[li];
            sv[li] = masked ? NEGV : s;
        }
    }
    // ---- softmax (per (li, h): 4-wave reduce) ----
#pragma unroll
    for (int li = 0; li < QG; ++li) {
        float a = sv[li];
#pragma unroll
        for (int o = 32; o > 0; o >>= 1) a = fmaxf(a, __shfl_xor(a, o));
        if (lane == 0) redm[li][h][mw] = a;
    }
    __syncthreads();
#pragma unroll
    for (int li = 0; li < QG; ++li) {
        float mx = fmaxf(fmaxf(redm[li][h][0], redm[li][h][1]),
                         fmaxf(redm[li][h][2], redm[li][h][3]));
        float e = __expf(sv[li] - mx);
        sv[li] = e;
        float t = waveReduceSum(e);
        if (lane == 0) reds[li][h][mw] = t;
    }
    __syncthreads();
#pragma unroll
    for (int li = 0; li < QG; ++li) {
        float sum = reds[li][h][0] + reds[li][h][1] + reds[li][h][2] + reds[li][h][3];
        float a = sv[li] / sum;
        A_s[li][h][m] = a;
        if (a != 0.f) atomicAdd(&Wl[li][h][tmc[li]], a);
    }
    __syncthreads();

    // ---- output: dense sweeps, 8 chunks, 2 loads in flight ----
    const int hd = tid & 63, chunk = tid >> 6;
    const int hh = hd >> 5;
    float acc0 = 0.f, acc1 = 0.f, acc2 = 0.f, acc3 = 0.f;

    const int mend = anypad ? SEQL : (lmax + 1 < SEQL ? lmax + 1 : SEQL);
    const float* vpb = Vp + (size_t)(b * SEQL) * HDIM + hd;
    int mm = chunk;
    for (; mm + 8 < mend; mm += 16) {
        float v0 = vpb[(size_t)(mm)   * HDIM];
        float v1 = vpb[(size_t)(mm+8) * HDIM];
        acc0 += A_s[0][hh][mm]*v0 + A_s[0][hh][mm+8]*v1;
        acc1 += A_s[1][hh][mm]*v0 + A_s[1][hh][mm+8]*v1;
        acc2 += A_s[2][hh][mm]*v0 + A_s[2][hh][mm+8]*v1;
        acc3 += A_s[3][hh][mm]*v0 + A_s[3][hh][mm+8]*v1;
    }
    for (; mm < mend; mm += 8) {
        float vp = vpb[(size_t)mm * HDIM];
        acc0 += A_s[0][hh][mm]*vp; acc1 += A_s[1][hh][mm]*vp;
        acc2 += A_s[2][hh][mm]*vp; acc3 += A_s[3][hh][mm]*vp;
    }
    const float* tvb = tVtab + hd;
    int c = chunk;
    for (; c + 8 < TKC; c += 16) {
        float t0 = tvb[(size_t)(c)   * HDIM];
        float t1 = tvb[(size_t)(c+8) * HDIM];
        acc0 += Wl[0][hh][c]*t0 + Wl[0][hh][c+8]*t1;
        acc1 += Wl[1][hh][c]*t0 + Wl[1][hh][c+8]*t1;
        acc2 += Wl[2][hh][c]*t0 + Wl[2][hh][c+8]*t1;
        acc3 += Wl[3][hh][c]*t0 + Wl[3][hh][c+8]*t1;
    }
    for (; c < TKC; c += 8) {
        float tv = tvb[(size_t)c * HDIM];
        acc0 += Wl[0][hh][c]*tv; acc1 += Wl[1][hh][c]*tv;
        acc2 += Wl[2][hh][c]*tv; acc3 += Wl[3][hh][c]*tv;
    }
    outred[chunk][0][hd] = acc0;
    outred[chunk][1][hd] = acc1;
    outred[chunk][2][hd] = acc2;
    outred[chunk][3][hd] = acc3;
    __syncthreads();
    if (tid < 256) {
        const int li = tid >> 6, dcol = tid & 63;
        const int row = row0 + li;
        float o = outred[0][li][dcol] + outred[1][li][dcol]
                + outred[2][li][dcol] + outred[3][li][dcol]
                + outred[4][li][dcol] + outred[5][li][dcol]
                + outred[6][li][dcol] + outred[7][li][dcol];
        x2[(size_t)row * HDIM + dcol] = q_in[(size_t)row * HDIM + dcol] + o;
    }
}

// Fused: LN2 + FFN + residual + keep (layer i)  ->  LN1 + QKV prep (layer i+1).
__global__ __launch_bounds__(256) void ffnprep_kernel(
    const float* __restrict__ x2, const int* __restrict__ seqs_data,
    const int* __restrict__ positions,
    const float* __restrict__ g2, const float* __restrict__ bg2,
    const float* __restrict__ W1T, const float* __restrict__ bb1,
    const float* __restrict__ W2T, const float* __restrict__ bb2,
    const float* __restrict__ g1n, const float* __restrict__ b1n,
    const float* __restrict__ QwT, const float* __restrict__ Qb,
    const float* __restrict__ KwT, const float* __restrict__ Kb,
    const float* __restrict__ VwT, const float* __restrict__ Vb,
    const float* __restrict__ apK, const float* __restrict__ apV,
    float* __restrict__ q_in, float* __restrict__ Qo,
    float* __restrict__ KpT, float* __restrict__ Vp)
{
    const int w = threadIdx.x >> 6;
    const int t = threadIdx.x & 63;
    const int row0 = blockIdx.x * 4;
    const int row = row0 + w;
    float x = x2[(size_t)row * HDIM + t];
    float mean = waveReduceSum(x) * (1.f / HDIM);
    float d = x - mean;
    float var = waveReduceSum(d * d) * (1.f / HDIM);
    float s = g2[t] * d / sqrtf(var + LNEPS) + bg2[t];

    __shared__ float ss[4][HDIM];
    __shared__ float hs[4][HDIM];
    __shared__ float kx[HDIM][5];
    ss[w][t] = s;
    float acc = 0.f;
#pragma unroll 16
    for (int mth = 0; mth < 64; ++mth)
        acc += ss[w][mth] * W1T[mth*64 + t];
    float hval = fmaxf(acc + bb1[t], 0.f);
    hs[w][t] = hval;
    float acc2 = 0.f;
#pragma unroll 16
    for (int mth = 0; mth < 64; ++mth)
        acc2 += hs[w][mth] * W2T[mth*64 + t];
    float y = acc2 + bb2[t] + s;
    if (seqs_data[row] == PADID) y = 0.f;

    // ---- prep of next layer on y ----
    float mean2 = waveReduceSum(y) * (1.f / HDIM);
    float d2 = y - mean2;
    float var2 = waveReduceSum(d2 * d2) * (1.f / HDIM);
    float q = g1n[t] * d2 / sqrtf(var2 + LNEPS) + b1n[t];

    ss[w][t] = y;   // reuse as xs
    hs[w][t] = q;   // reuse as qs
    q_in[(size_t)row * HDIM + t] = q;

    int pos = positions[row];
    float aK = pos ? apK[(size_t)pos * HDIM + t] : 0.f;
    float aV = pos ? apV[(size_t)pos * HDIM + t] : 0.f;

    float aq = 0.f, ak = 0.f, av = 0.f;
#pragma unroll 16
    for (int mth = 0; mth < 64; ++mth) {
        float qm = hs[w][mth], ym = ss[w][mth];
        aq += qm * QwT[mth*64 + t];
        ak += ym * KwT[mth*64 + t];
        av += ym * VwT[mth*64 + t];
    }
    Qo[(size_t)row * HDIM + t] = aq + Qb[t];
    Vp[(size_t)row * HDIM + t] = av + Vb[t] + aV;
    kx[t][w] = ak + Kb[t] + aK;
    __syncthreads();
    const int f = threadIdx.x >> 2, j = threadIdx.x & 3;
    KpT[(size_t)f * 4096 + row0 + j] = kx[f][j];
}

// Final: LN2 + FFN + residual + keep + last LayerNorm -> d_out.
__global__ __launch_bounds__(256) void ffnfinal_kernel(
    const float* __restrict__ x2, const int* __restrict__ seqs_data,
    const float* __restrict__ g2, const float* __restrict__ bg2,
    const float* __restrict__ W1T, const float* __restrict__ bb1,
    const float* __restrict__ W2T, const float* __restrict__ bb2,
    const float* __restrict__ lg, const float* __restrict__ lb,
    float* __restrict__ dout)
{
    const int w = threadIdx.x >> 6;
    const int t = threadIdx.x & 63;
    const int row = blockIdx.x * 4 + w;
    float x = x2[(size_t)row * HDIM + t];
    float mean = waveReduceSum(x) * (1.f / HDIM);
    float d = x - mean;
    float var = waveReduceSum(d * d) * (1.f / HDIM);
    float s = g2[t] * d / sqrtf(var + LNEPS) + bg2[t];

    __shared__ float ss[4][HDIM];
    __shared__ float hs[4][HDIM];
    ss[w][t] = s;
    float acc = 0.f;
#pragma unroll 16
    for (int mth = 0; mth < 64; ++mth)
        acc += ss[w][mth] * W1T[mth*64 + t];
    float hval = fmaxf(acc + bb1[t], 0.f);
    hs[w][t] = hval;
    float acc2 = 0.f;
#pragma unroll 16
    for (int mth = 0; mth < 64; ++mth)
        acc2 += hs[w][mth] * W2T[mth*64 + t];
    float y = acc2 + bb2[t] + s;
    if (seqs_data[row] == PADID) y = 0.f;
    float m2 = waveReduceSum(y) * (1.f / HDIM);
    float dd = y - m2;
    float v2 = waveReduceSum(dd * dd) * (1.f / HDIM);
    dout[(size_t)row * HDIM + t] = lg[t] * dd / sqrtf(v2 + LNEPS) + lb[t];
}

extern "C" void kernel_launch(void* const* d_in, const int* in_sizes, int n_in,
                              void* d_out, int out_size, void* d_ws, size_t ws_size,
                              hipStream_t stream) {
    const int*   seqs_data = (const int*)d_in[0];
    const float* seqs      = (const float*)d_in[1];
    const int*   positions = (const int*)d_in[2];
    const int*   tmat      = (const int*)d_in[3];
    const float* apK       = (const float*)d_in[4];
    const float* apV       = (const float*)d_in[5];
    const float* tKtab     = (const float*)d_in[6];
    const float* tVtab     = (const float*)d_in[7];
    const float* Qw = (const float*)d_in[8];
    const float* Qb = (const float*)d_in[9];
    const float* Kw = (const float*)d_in[10];
    const float* Kb = (const float*)d_in[11];
    const float* Vw = (const float*)d_in[12];
    const float* Vb = (const float*)d_in[13];
    const float* g1 = (const float*)d_in[14];
    const float* b1 = (const float*)d_in[15];
    const float* g2 = (const float*)d_in[16];
    const float* b2 = (const float*)d_in[17];
    const float* W1 = (const float*)d_in[18];
    const float* fb1 = (const float*)d_in[19];
    const float* W2 = (const float*)d_in[20];
    const float* fb2 = (const float*)d_in[21];
    const float* lastg = (const float*)d_in[22];
    const float* lastb = (const float*)d_in[23];

    const size_t N = (size_t)BATCH * SEQL * HDIM;   // 262144
    float* ws    = (float*)d_ws;
    float* x     = ws;           // attn output x2
    float* q_in  = ws + 1 * N;
    float* Qo    = ws + 2 * N;
    float* Vp    = ws + 3 * N;
    float* KpT   = ws + 4 * N;
    float* wtbase = ws + 5 * N;
    float* QwT = wtbase;                 // 2 layers x 4096
    float* KwT = wtbase + 8192;
    float* VwT = wtbase + 16384;
    float* W1T = wtbase + 24576;
    float* W2T = wtbase + 32768;
    float* tKtabT = wtbase + 40960;      // 64*260

    const int rows = BATCH * SEQL;   // 4096

    setup_kernel<<<15, 256, 0, stream>>>(Qw, Kw, Vw, W1, W2, tKtab,
                                         QwT, KwT, VwT, W1T, W2T, tKtabT);

    prep_kernel<<<rows / 4, 256, 0, stream>>>(
        seqs, seqs_data, positions,
        QwT, Qb, KwT, Kb, VwT, Vb, g1, b1,
        apK, apV, q_in, Qo, KpT, Vp);

    attn_kernel<<<rows / QG, 512, 0, stream>>>(
        Qo, KpT, Vp, q_in, seqs_data, tmat, tVtab, tKtabT, x);

    ffnprep_kernel<<<rows / 4, 256, 0, stream>>>(
        x, seqs_data, positions,
        g2, b2, W1T, fb1, W2T, fb2,
        g1 + HDIM, b1 + HDIM,
        QwT + 4096, Qb + HDIM, KwT + 4096, Kb + HDIM, VwT + 4096, Vb + HDIM,
        apK, apV, q_in, Qo, KpT, Vp);

    attn_kernel<<<rows / QG, 512, 0, stream>>>(
        Qo, KpT, Vp, q_in, seqs_data, tmat, tVtab, tKtabT, x);

    ffnfinal_kernel<<<rows / 4, 256, 0, stream>>>(
        x, seqs_data,
        g2 + HDIM, b2 + HDIM, W1T + 4096, fb1 + HDIM, W2T + 4096, fb2 + HDIM,
        lastg, lastb, (float*)d_out);
}